// Round 2
// 522.111 us; speedup vs baseline: 1.0786x; 1.0786x over previous
//
#include <hip/hip_runtime.h>
#include <hip/hip_bf16.h>

// Problem constants
#define IN_F   4096
#define OUT_F  4096
#define RTOT   128
#define NE     8
#define RP     16
#define NROWS  8192
#define KC     (IN_F + RTOT)   // 4224 concatenated K
#define NG     144             // AG rows: 128 loraA + 8 gate + 8 zero pad
#define SCALING 0.125f         // ALPHA / R = 16/128
#define KSPLIT 4               // hgemm K-split (slice-H, no atomics)

typedef __attribute__((ext_vector_type(8))) short bf16x8;   // 8 bf16 (4 VGPRs)
typedef __attribute__((ext_vector_type(4))) float f32x4;    // 4 fp32 acc

// async global -> LDS, 16 B per lane (global_load_lds_dwordx4)
__device__ __forceinline__ void gl_lds16(const __hip_bfloat16* g, __hip_bfloat16* l) {
    __builtin_amdgcn_global_load_lds(
        (const __attribute__((address_space(1))) unsigned int*)g,
        (__attribute__((address_space(3))) unsigned int*)l, 16, 0, 0);
}

union bf8pack { bf16x8 v; __hip_bfloat16 h[8]; };
union bf4pack { ushort4 u; __hip_bfloat16 h[4]; };

// ---------------- fused prep ----------------
// region A [0, 16896):     Wcat[o][0:4096]=W0, Wcat[o][4096+e*16+r]=B[e][o][r]  (4/thread)
// region B [16896, 17472): AG rows 0..127=A, 128..135=Wg, 136..143=0            (4/thread)
// region C [17472, 33856): Xcat[:, :4096] = bf16(x)                             (8/thread)
#define PREP_GRID 33856
__global__ void k_prep(const float* __restrict__ W0, const float* __restrict__ B,
                       const float* __restrict__ A, const float* __restrict__ Wg,
                       const float* __restrict__ x,
                       __hip_bfloat16* __restrict__ Wcat, __hip_bfloat16* __restrict__ AG,
                       __hip_bfloat16* __restrict__ Xcat) {
    int bid = blockIdx.x, tid = threadIdx.x;
    if (bid < 16896) {
        int i4 = (bid * 256 + tid) * 4;                // element idx into Wcat
        int o = i4 / KC;
        int c = i4 - o * KC;
        float4 v;
        if (c < IN_F) v = *(const float4*)&W0[(size_t)o * IN_F + c];
        else {
            int k = c - IN_F, e = k >> 4, r = k & 15;  // r in {0,4,8,12}
            v = *(const float4*)&B[(size_t)((e * OUT_F + o) << 4) + r];
        }
        bf4pack p;
        p.h[0] = __float2bfloat16(v.x); p.h[1] = __float2bfloat16(v.y);
        p.h[2] = __float2bfloat16(v.z); p.h[3] = __float2bfloat16(v.w);
        *(ushort4*)&Wcat[i4] = p.u;
    } else if (bid < 17472) {
        int j4 = ((bid - 16896) * 256 + tid) * 4;
        int row = j4 >> 12, d = j4 & 4095;
        float4 v = {0.f, 0.f, 0.f, 0.f};
        if (row < RTOT)      v = *(const float4*)&A[j4];
        else if (row < 136)  v = *(const float4*)&Wg[((row - RTOT) << 12) + d];
        bf4pack p;
        p.h[0] = __float2bfloat16(v.x); p.h[1] = __float2bfloat16(v.y);
        p.h[2] = __float2bfloat16(v.z); p.h[3] = __float2bfloat16(v.w);
        *(ushort4*)&AG[j4] = p.u;
    } else {
        int t = (bid - 17472) * 256 + tid;             // 8 elems/thread, 8192*512 threads
        int n = t >> 9, c8 = t & 511;
        const float4* src = (const float4*)&x[((size_t)n << 12) + (c8 << 3)];
        float4 v0 = src[0], v1 = src[1];
        bf8pack p;
        p.h[0] = __float2bfloat16(v0.x); p.h[1] = __float2bfloat16(v0.y);
        p.h[2] = __float2bfloat16(v0.z); p.h[3] = __float2bfloat16(v0.w);
        p.h[4] = __float2bfloat16(v1.x); p.h[5] = __float2bfloat16(v1.y);
        p.h[6] = __float2bfloat16(v1.z); p.h[7] = __float2bfloat16(v1.w);
        *(bf16x8*)&Xcat[(size_t)n * KC + (c8 << 3)] = p.v;
    }
}

// ------- H[s][8192][144] = Xcat[:, s-chunk] @ AG^T[s-chunk] (slice per K-split, no atomics) ---
__global__ __launch_bounds__(256) void k_hgemm(const __hip_bfloat16* __restrict__ Xcat,
                                               const __hip_bfloat16* __restrict__ AG,
                                               float* __restrict__ H) {
    __shared__ __hip_bfloat16 sX[128 * 32];
    __shared__ __hip_bfloat16 sG[NG * 32];
    const int tid  = threadIdx.x;
    const int lane = tid & 63;
    const int w    = tid >> 6;          // wave handles rows w*32 .. w*32+31
    const int quad = lane >> 4;
    const int l16  = lane & 15;
    const int m0   = blockIdx.x * 128;
    const int kbeg = blockIdx.y * (IN_F / KSPLIT);   // 1024-wide K chunk

    f32x4 acc[2][9];
    for (int i = 0; i < 2; ++i)
        for (int j = 0; j < 9; ++j)
            acc[i][j] = (f32x4){0.f, 0.f, 0.f, 0.f};

    const int sr = tid >> 2;
    const int sk2 = (((tid & 3) ^ ((sr >> 1) & 3)) << 3);   // XOR chunk swizzle
    const int qq  = quad ^ ((l16 >> 1) & 3);                // reader swizzle (lane const)

    for (int kt = kbeg; kt < kbeg + IN_F / KSPLIT; kt += 32) {
        __syncthreads();
        gl_lds16(&Xcat[(size_t)(m0 + sr) * KC + kt + sk2],      &sX[tid * 8]);
        gl_lds16(&Xcat[(size_t)(m0 + 64 + sr) * KC + kt + sk2], &sX[(tid + 256) * 8]);
        gl_lds16(&AG[(size_t)sr * IN_F + kt + sk2],             &sG[tid * 8]);
        gl_lds16(&AG[(size_t)(64 + sr) * IN_F + kt + sk2],      &sG[(tid + 256) * 8]);
        if (tid < 64)
            gl_lds16(&AG[(size_t)(128 + sr) * IN_F + kt + sk2], &sG[(tid + 512) * 8]);
        __syncthreads();

        bf16x8 a[2], b[9];
#pragma unroll
        for (int ti = 0; ti < 2; ++ti)
            a[ti] = *(const bf16x8*)(&sX[(w * 32 + ti * 16 + l16) * 32 + qq * 8]);
#pragma unroll
        for (int tj = 0; tj < 9; ++tj)
            b[tj] = *(const bf16x8*)(&sG[(tj * 16 + l16) * 32 + qq * 8]);
#pragma unroll
        for (int ti = 0; ti < 2; ++ti)
#pragma unroll
            for (int tj = 0; tj < 9; ++tj)
                acc[ti][tj] = __builtin_amdgcn_mfma_f32_16x16x32_bf16(a[ti], b[tj], acc[ti][tj], 0, 0, 0);
    }

    float* Hs = &H[(size_t)blockIdx.y * NROWS * NG];
#pragma unroll
    for (int ti = 0; ti < 2; ++ti)
#pragma unroll
        for (int tj = 0; tj < 9; ++tj) {
            int col = tj * 16 + l16;
#pragma unroll
            for (int i = 0; i < 4; ++i) {
                int row = m0 + w * 32 + ti * 16 + quad * 4 + i;
                Hs[(size_t)row * NG + col] = acc[ti][tj][i];
            }
        }
}

// -------- gate softmax + slice-reduce + scaled hg into Xcat[:, 4096:] (16 thr/row) ----------
__global__ void k_gate(const float* __restrict__ H, __hip_bfloat16* __restrict__ Xcat) {
    int id = blockIdx.x * 256 + threadIdx.x;         // 8192*16 threads
    int n = id >> 4, k8 = id & 15;
    const float* hb = &H[(size_t)n * NG];
    float lg[NE] = {0.f, 0.f, 0.f, 0.f, 0.f, 0.f, 0.f, 0.f};
#pragma unroll
    for (int s = 0; s < KSPLIT; ++s) {
        const float* hs = hb + (size_t)s * NROWS * NG;
        float4 g0 = *(const float4*)&hs[128];
        float4 g1 = *(const float4*)&hs[132];
        lg[0] += g0.x; lg[1] += g0.y; lg[2] += g0.z; lg[3] += g0.w;
        lg[4] += g1.x; lg[5] += g1.y; lg[6] += g1.z; lg[7] += g1.w;
    }
    float mx = lg[0];
#pragma unroll
    for (int e = 1; e < NE; ++e) mx = fmaxf(mx, lg[e]);
    float ssum = 0.f;
#pragma unroll
    for (int e = 0; e < NE; ++e) { lg[e] = __expf(lg[e] - mx); ssum += lg[e]; }
    float inv = SCALING / ssum;
    int e = k8 >> 1;                                 // expert for this 8-col chunk
    float ge = 0.f;
#pragma unroll
    for (int e2 = 0; e2 < NE; ++e2) if (e2 == e) ge = lg[e2];
    ge *= inv;
    float hv[8] = {0.f, 0.f, 0.f, 0.f, 0.f, 0.f, 0.f, 0.f};
#pragma unroll
    for (int s = 0; s < KSPLIT; ++s) {
        const float* hs = hb + (size_t)s * NROWS * NG;
        float4 h0 = *(const float4*)&hs[k8 * 8];
        float4 h1 = *(const float4*)&hs[k8 * 8 + 4];
        hv[0] += h0.x; hv[1] += h0.y; hv[2] += h0.z; hv[3] += h0.w;
        hv[4] += h1.x; hv[5] += h1.y; hv[6] += h1.z; hv[7] += h1.w;
    }
    bf8pack p;
#pragma unroll
    for (int i = 0; i < 8; ++i) p.h[i] = __float2bfloat16(hv[i] * ge);
    *(bf16x8*)&Xcat[(size_t)n * KC + IN_F + k8 * 8] = p.v;
}

// ==================== 256x256 8-phase main GEMM (T2+T3+T4+T5) ====================
// out[8192][4096] = Xcat @ Wcat^T, K=4224 = 66 tiles of BK=64 -> 33 iters x 2 tiles.
// 512 threads = 8 waves (2M x 4N), per-wave C = 128x64 = acc[8][4].
// LDS 128 KiB STATIC = 2 dbuf x {A,B} x {lo,hi} half-tiles of 128x64 bf16 (16 KiB each).
// Slot read schedule per buf: B slots read in Q-phases 1,2; A slots in 1,3.
// Stage schedule (slot overwritten ONLY after its last reader's phase-end barrier):
//   P1: buf1.A-hi(t 2i+1) | P3: buf0.B-lo+B-hi(t 2i+2) | P4: buf0.A-lo | P5: buf0.A-hi
//   P7: buf1.B-lo+B-hi(t 2i+3) | P8: buf1.A-lo        | P2,P6: no stage
// vmcnt(6) ledger: @P4 in-flight = prevP7(4)+prevP8(2)+P1(2)+P3(4)+P4(2)=14 loads;
//   vmcnt(6) retires through P1 => buf1 tile landed before P5 reads. Symmetric @P8
//   (retires through P5 => buf0 next tile landed before next P1). Never drains to 0 in-loop.
// XOR chunk swizzle (chunk ^= row&7) on BOTH stage-source and ds_read (rule 21).

#define BARRIER() __builtin_amdgcn_s_barrier()
#define SBAR()    __builtin_amdgcn_sched_barrier(0)
#define LGKM0()   do { asm volatile("s_waitcnt lgkmcnt(0)" ::: "memory"); SBAR(); } while (0)
#define VMCNT6()  asm volatile("s_waitcnt vmcnt(6)" ::: "memory")
#define VMCNT0()  asm volatile("s_waitcnt vmcnt(0)" ::: "memory")
#define PRIO(x)   __builtin_amdgcn_s_setprio(x)

// slot(buf, op, half) element base = (buf*4 + op*2 + half) * 8192; op 0=A, 1=B
#define STAGE(buf, op, half, koff) do {                                               \
        const __hip_bfloat16* _g = ((op) ? gB : gA) + (size_t)(half) * 128 * KC + (koff); \
        __hip_bfloat16* _l = lds + ((buf) * 4 + (op) * 2 + (half)) * 8192 + tid * 8;  \
        gl_lds16(_g, _l);                                                             \
        gl_lds16(_g + (size_t)64 * KC, _l + 4096);                                    \
    } while (0)

#define DS_A(b, mbase) do {                                                           \
        _Pragma("unroll") for (int mi = 0; mi < 4; ++mi) {                            \
            const __hip_bfloat16* _p = As[b] + (((mbase) + mi) * 16 + l16) * 64;      \
            a[mi][0] = *(const bf16x8*)(_p + kc0);                                    \
            a[mi][1] = *(const bf16x8*)(_p + kc1);                                    \
        } } while (0)

#define DS_B(b, dst, nbase) do {                                                      \
        _Pragma("unroll") for (int nj = 0; nj < 2; ++nj) {                            \
            const __hip_bfloat16* _p = Bs[b] + (brow0 + ((nbase) + nj) * 16 + l16) * 64; \
            dst[nj][0] = *(const bf16x8*)(_p + kc0);                                  \
            dst[nj][1] = *(const bf16x8*)(_p + kc1);                                  \
        } } while (0)

#define MM(mb, dst, nb) do {                                                          \
        _Pragma("unroll") for (int mi = 0; mi < 4; ++mi)                              \
        _Pragma("unroll") for (int nj = 0; nj < 2; ++nj) {                            \
            acc[(mb) + mi][(nb) + nj] = __builtin_amdgcn_mfma_f32_16x16x32_bf16(      \
                a[mi][0], dst[nj][0], acc[(mb) + mi][(nb) + nj], 0, 0, 0);            \
            acc[(mb) + mi][(nb) + nj] = __builtin_amdgcn_mfma_f32_16x16x32_bf16(      \
                a[mi][1], dst[nj][1], acc[(mb) + mi][(nb) + nj], 0, 0, 0);            \
        } } while (0)

__global__ __launch_bounds__(512, 2) void k_gemm(const __hip_bfloat16* __restrict__ Xcat,
                                                 const __hip_bfloat16* __restrict__ Wcat,
                                                 float* __restrict__ out) {
    __shared__ __hip_bfloat16 lds[8 * 8192];    // 8 x 16 KiB half-tile slots = 128 KiB static
    const int tid  = threadIdx.x;
    const int lane = tid & 63;
    const int w    = tid >> 6;                  // 0..7
    const int wm   = w >> 2, wn = w & 3;        // 2M x 4N waves
    const int quad = lane >> 4;
    const int l16  = lane & 15;
    const int xr   = l16 & 7;

    // XCD-bijective swizzle (512 % 8 == 0 -> simple form bijective)
    const int bid = blockIdx.x;
    const int swz = (bid & 7) * 64 + (bid >> 3);
    const int m0  = (swz >> 4) * 256;           // 32 M-blocks
    const int n0  = (swz & 15) * 256;           // 16 N-blocks

    // staging addresses: thread t covers rows {srow, srow+64} of a half-tile,
    // global chunk = (t&7) ^ (srow&7)  (LDS stays linear; source pre-swizzled)
    const int srow = tid >> 3;
    const int scol = ((tid & 7) ^ (srow & 7)) << 3;
    const __hip_bfloat16* gA = Xcat + (size_t)(m0 + srow) * KC + scol;
    const __hip_bfloat16* gB = Wcat + (size_t)(n0 + srow) * KC + scol;

    // reader slot bases: wave reads ONE A half (by wm) and ONE B half (by wn>>1)
    const __hip_bfloat16* As[2] = { lds + (0 + wm) * 8192,        lds + (4 + wm) * 8192 };
    const __hip_bfloat16* Bs[2] = { lds + (2 + (wn >> 1)) * 8192, lds + (6 + (wn >> 1)) * 8192 };
    const int brow0 = (wn & 1) * 64;
    const int kc0 = (quad ^ xr) * 8;            // k-chunk swizzled (elems)
    const int kc1 = ((4 + quad) ^ xr) * 8;

    f32x4 acc[8][4];
#pragma unroll
    for (int i = 0; i < 8; ++i)
#pragma unroll
        for (int j = 0; j < 4; ++j)
            acc[i][j] = (f32x4){0.f, 0.f, 0.f, 0.f};
    bf16x8 a[4][2], bl[2][2], bh[2][2];

    // ---- prologue: tile0 (4 half-tiles) + tile1 {Blo,Bhi,Alo}; vmcnt(6) retires tile0 ----
    STAGE(0, 1, 0, 0);    // t0.B-lo
    STAGE(0, 1, 1, 0);    // t0.B-hi
    STAGE(0, 0, 0, 0);    // t0.A-lo
    STAGE(0, 0, 1, 0);    // t0.A-hi
    STAGE(1, 1, 0, 64);   // t1.B-lo
    STAGE(1, 1, 1, 64);   // t1.B-hi
    STAGE(1, 0, 0, 64);   // t1.A-lo
    VMCNT6();
    BARRIER(); SBAR();

#pragma unroll 1
    for (int i = 0; i < 33; ++i) {
        const int kb    = i * 128;
        const int t1off = kb + 64;                                    // tile 2i+1 (always valid)
        const int s0off = (kb + 128 <= KC - 64) ? kb + 128 : KC - 64; // tile 2i+2 (clamped)
        const int s1off = (kb + 192 <= KC - 64) ? kb + 192 : KC - 64; // tile 2i+3 (clamped)

        // P1: Q(mlo,nlo) buf0; stage buf1.A-hi (slot free since prev P7; disjoint from reads)
        DS_A(0, 0); DS_B(0, bl, 0);
        STAGE(1, 0, 1, t1off);
        BARRIER(); LGKM0();
        PRIO(1); MM(0, bl, 0); PRIO(0);
        BARRIER(); SBAR();

        // P2: Q(mlo,nhi) buf0; NO stage (buf0.B still being read this phase)
        DS_B(0, bh, 2);
        BARRIER(); LGKM0();
        PRIO(1); MM(0, bh, 2); PRIO(0);
        BARRIER(); SBAR();

        // P3: Q(mhi,nhi) buf0; stage buf0.B-lo + B-hi (free since P2-end barrier)
        DS_A(0, 4);
        STAGE(0, 1, 0, s0off);
        STAGE(0, 1, 1, s0off);
        BARRIER(); LGKM0();
        PRIO(1); MM(4, bh, 2); PRIO(0);
        BARRIER(); SBAR();

        // P4: Q(mhi,nlo) buf0 (regs only); stage buf0.A-lo (free since P3);
        //     vmcnt(6) retires through P1 => buf1 (tile 2i+1) fully landed
        STAGE(0, 0, 0, s0off);
        BARRIER(); LGKM0();
        PRIO(1); MM(4, bl, 0); PRIO(0);
        VMCNT6();
        BARRIER(); SBAR();

        // P5: Q(mlo,nlo) buf1; stage buf0.A-hi (free since P3; disjoint from buf1 reads)
        DS_A(1, 0); DS_B(1, bl, 0);
        STAGE(0, 0, 1, s0off);
        BARRIER(); LGKM0();
        PRIO(1); MM(0, bl, 0); PRIO(0);
        BARRIER(); SBAR();

        // P6: Q(mlo,nhi) buf1; NO stage (buf1.B still being read this phase)
        DS_B(1, bh, 2);
        BARRIER(); LGKM0();
        PRIO(1); MM(0, bh, 2); PRIO(0);
        BARRIER(); SBAR();

        // P7: Q(mhi,nhi) buf1; stage buf1.B-lo + B-hi (free since P6-end barrier)
        DS_A(1, 4);
        STAGE(1, 1, 0, s1off);
        STAGE(1, 1, 1, s1off);
        BARRIER(); LGKM0();
        PRIO(1); MM(4, bh, 2); PRIO(0);
        BARRIER(); SBAR();

        // P8: Q(mhi,nlo) buf1 (regs only); stage buf1.A-lo (free since P7);
        //     vmcnt(6) retires through P5 => buf0 (tile 2i+2) fully landed
        STAGE(1, 0, 0, s1off);
        BARRIER(); LGKM0();
        PRIO(1); MM(4, bl, 0); PRIO(0);
        VMCNT6();
        BARRIER(); SBAR();
    }
    VMCNT0();   // drain the 6 in-flight (clamped) epilogue loads before endpgm

    // ---- C-write: row = m0 + wm*128 + ti*16 + quad*4 + r ; col = n0 + wn*64 + tj*16 + l16 ----
#pragma unroll
    for (int ti = 0; ti < 8; ++ti)
#pragma unroll
        for (int tj = 0; tj < 4; ++tj) {
            int col = n0 + wn * 64 + tj * 16 + l16;
#pragma unroll
            for (int r = 0; r < 4; ++r) {
                int row = m0 + wm * 128 + ti * 16 + quad * 4 + r;
                out[(size_t)row * OUT_F + col] = acc[ti][tj][r];
            }
        }
}

extern "C" void kernel_launch(void* const* d_in, const int* in_sizes, int n_in,
                              void* d_out, int out_size, void* d_ws, size_t ws_size,
                              hipStream_t stream) {
    const float* x  = (const float*)d_in[0];   // [8192, 4096]
    const float* W0 = (const float*)d_in[1];   // [4096, 4096]
    const float* Wg = (const float*)d_in[2];   // [8, 4096]
    const float* A  = (const float*)d_in[3];   // [8, 16, 4096]
    const float* B  = (const float*)d_in[4];   // [8, 4096, 16]
    float* out = (float*)d_out;

    char* ws = (char*)d_ws;
    size_t off = 0;
    __hip_bfloat16* Xcat = (__hip_bfloat16*)(ws + off); off += (size_t)NROWS * KC * 2;        // 69.2 MB
    __hip_bfloat16* Wcat = (__hip_bfloat16*)(ws + off); off += (size_t)OUT_F * KC * 2;        // 34.6 MB
    __hip_bfloat16* AG   = (__hip_bfloat16*)(ws + off); off += (size_t)NG * IN_F * 2;         // 1.2 MB
    float*          H    = (float*)(ws + off);          off += (size_t)KSPLIT * NROWS * NG * 4; // 18.9 MB

    k_prep<<<PREP_GRID, 256, 0, stream>>>(W0, B, A, Wg, x, Wcat, AG, Xcat);
    k_hgemm<<<dim3(NROWS / 128, KSPLIT), 256, 0, stream>>>(Xcat, AG, H);
    k_gate<<<(NROWS * 16) / 256, 256, 0, stream>>>(H, Xcat);
    k_gemm<<<512, 512, 0, stream>>>(Xcat, Wcat, out);
}

// Round 4
// 510.605 us; speedup vs baseline: 1.1029x; 1.0225x over previous
//
#include <hip/hip_runtime.h>
#include <hip/hip_bf16.h>

// Problem constants
#define IN_F   4096
#define OUT_F  4096
#define RTOT   128
#define NE     8
#define RP     16
#define NROWS  8192
#define KC     (IN_F + RTOT)   // 4224 concatenated K
#define NG     144             // AG rows: 128 loraA + 8 gate + 8 zero pad
#define SCALING 0.125f         // ALPHA / R = 16/128
#define KSPLIT 4               // hgemm K-split (slice-H, no atomics)

typedef __attribute__((ext_vector_type(8))) short bf16x8;   // 8 bf16 (4 VGPRs)
typedef __attribute__((ext_vector_type(4))) float f32x4;    // 4 fp32 acc

// async global -> LDS, 16 B per lane (global_load_lds_dwordx4)
__device__ __forceinline__ void gl_lds16(const __hip_bfloat16* g, __hip_bfloat16* l) {
    __builtin_amdgcn_global_load_lds(
        (const __attribute__((address_space(1))) unsigned int*)g,
        (__attribute__((address_space(3))) unsigned int*)l, 16, 0, 0);
}

union bf8pack { bf16x8 v; __hip_bfloat16 h[8]; };
union bf4pack { ushort4 u; __hip_bfloat16 h[4]; };

// ---------------- fused prep ----------------
// region A [0, 16896):     Wcat[o][0:4096]=W0, Wcat[o][4096+e*16+r]=B[e][o][r]  (4/thread)
// region B [16896, 17472): AG rows 0..127=A, 128..135=Wg, 136..143=0            (4/thread)
// region C [17472, 33856): Xcat[:, :4096] = bf16(x)                             (8/thread)
#define PREP_GRID 33856
__global__ void k_prep(const float* __restrict__ W0, const float* __restrict__ B,
                       const float* __restrict__ A, const float* __restrict__ Wg,
                       const float* __restrict__ x,
                       __hip_bfloat16* __restrict__ Wcat, __hip_bfloat16* __restrict__ AG,
                       __hip_bfloat16* __restrict__ Xcat) {
    int bid = blockIdx.x, tid = threadIdx.x;
    if (bid < 16896) {
        int i4 = (bid * 256 + tid) * 4;                // element idx into Wcat
        int o = i4 / KC;
        int c = i4 - o * KC;
        float4 v;
        if (c < IN_F) v = *(const float4*)&W0[(size_t)o * IN_F + c];
        else {
            int k = c - IN_F, e = k >> 4, r = k & 15;  // r in {0,4,8,12}
            v = *(const float4*)&B[(size_t)((e * OUT_F + o) << 4) + r];
        }
        bf4pack p;
        p.h[0] = __float2bfloat16(v.x); p.h[1] = __float2bfloat16(v.y);
        p.h[2] = __float2bfloat16(v.z); p.h[3] = __float2bfloat16(v.w);
        *(ushort4*)&Wcat[i4] = p.u;
    } else if (bid < 17472) {
        int j4 = ((bid - 16896) * 256 + tid) * 4;
        int row = j4 >> 12, d = j4 & 4095;
        float4 v = {0.f, 0.f, 0.f, 0.f};
        if (row < RTOT)      v = *(const float4*)&A[j4];
        else if (row < 136)  v = *(const float4*)&Wg[((row - RTOT) << 12) + d];
        bf4pack p;
        p.h[0] = __float2bfloat16(v.x); p.h[1] = __float2bfloat16(v.y);
        p.h[2] = __float2bfloat16(v.z); p.h[3] = __float2bfloat16(v.w);
        *(ushort4*)&AG[j4] = p.u;
    } else {
        int t = (bid - 17472) * 256 + tid;             // 8 elems/thread, 8192*512 threads
        int n = t >> 9, c8 = t & 511;
        const float4* src = (const float4*)&x[((size_t)n << 12) + (c8 << 3)];
        float4 v0 = src[0], v1 = src[1];
        bf8pack p;
        p.h[0] = __float2bfloat16(v0.x); p.h[1] = __float2bfloat16(v0.y);
        p.h[2] = __float2bfloat16(v0.z); p.h[3] = __float2bfloat16(v0.w);
        p.h[4] = __float2bfloat16(v1.x); p.h[5] = __float2bfloat16(v1.y);
        p.h[6] = __float2bfloat16(v1.z); p.h[7] = __float2bfloat16(v1.w);
        *(bf16x8*)&Xcat[(size_t)n * KC + (c8 << 3)] = p.v;
    }
}

// ------- H[s][8192][144] = Xcat[:, s-chunk] @ AG^T[s-chunk] (slice per K-split) ---
// 64-row M-blocks: grid (128, KSPLIT) = 512 blocks -> 2 blocks/CU, 2 waves/SIMD
// (was 128-row / 256 blocks = 1 wave/SIMD: zero latency hiding on the staging loop).
__global__ __launch_bounds__(256) void k_hgemm(const __hip_bfloat16* __restrict__ Xcat,
                                               const __hip_bfloat16* __restrict__ AG,
                                               float* __restrict__ H) {
    __shared__ __hip_bfloat16 sX[64 * 32];
    __shared__ __hip_bfloat16 sG[NG * 32];
    const int tid  = threadIdx.x;
    const int lane = tid & 63;
    const int w    = tid >> 6;          // wave handles rows w*16 .. w*16+15
    const int quad = lane >> 4;
    const int l16  = lane & 15;
    const int m0   = blockIdx.x * 64;
    const int kbeg = blockIdx.y * (IN_F / KSPLIT);   // 1024-wide K chunk

    f32x4 acc[9];
    for (int j = 0; j < 9; ++j) acc[j] = (f32x4){0.f, 0.f, 0.f, 0.f};

    const int sr = tid >> 2;
    const int sk2 = (((tid & 3) ^ ((sr >> 1) & 3)) << 3);   // XOR chunk swizzle
    const int qq  = quad ^ ((l16 >> 1) & 3);                // reader swizzle (lane const)

    for (int kt = kbeg; kt < kbeg + IN_F / KSPLIT; kt += 32) {
        __syncthreads();
        gl_lds16(&Xcat[(size_t)(m0 + sr) * KC + kt + sk2],      &sX[tid * 8]);
        gl_lds16(&AG[(size_t)sr * IN_F + kt + sk2],             &sG[tid * 8]);
        gl_lds16(&AG[(size_t)(64 + sr) * IN_F + kt + sk2],      &sG[(tid + 256) * 8]);
        if (tid < 64)
            gl_lds16(&AG[(size_t)(128 + sr) * IN_F + kt + sk2], &sG[(tid + 512) * 8]);
        __syncthreads();

        bf16x8 a = *(const bf16x8*)(&sX[(w * 16 + l16) * 32 + qq * 8]);
        bf16x8 b[9];
#pragma unroll
        for (int tj = 0; tj < 9; ++tj)
            b[tj] = *(const bf16x8*)(&sG[(tj * 16 + l16) * 32 + qq * 8]);
#pragma unroll
        for (int tj = 0; tj < 9; ++tj)
            acc[tj] = __builtin_amdgcn_mfma_f32_16x16x32_bf16(a, b[tj], acc[tj], 0, 0, 0);
    }

    float* Hs = &H[(size_t)blockIdx.y * NROWS * NG];
#pragma unroll
    for (int tj = 0; tj < 9; ++tj) {
        int col = tj * 16 + l16;
#pragma unroll
        for (int i = 0; i < 4; ++i) {
            int row = m0 + w * 16 + quad * 4 + i;
            Hs[(size_t)row * NG + col] = acc[tj][i];
        }
    }
}

// -------- gate softmax + slice-reduce + scaled hg into Xcat[:, 4096:] (16 thr/row) ----------
__global__ void k_gate(const float* __restrict__ H, __hip_bfloat16* __restrict__ Xcat) {
    int id = blockIdx.x * 256 + threadIdx.x;         // 8192*16 threads
    int n = id >> 4, k8 = id & 15;
    const float* hb = &H[(size_t)n * NG];
    float lg[NE] = {0.f, 0.f, 0.f, 0.f, 0.f, 0.f, 0.f, 0.f};
#pragma unroll
    for (int s = 0; s < KSPLIT; ++s) {
        const float* hs = hb + (size_t)s * NROWS * NG;
        float4 g0 = *(const float4*)&hs[128];
        float4 g1 = *(const float4*)&hs[132];
        lg[0] += g0.x; lg[1] += g0.y; lg[2] += g0.z; lg[3] += g0.w;
        lg[4] += g1.x; lg[5] += g1.y; lg[6] += g1.z; lg[7] += g1.w;
    }
    float mx = lg[0];
#pragma unroll
    for (int e = 1; e < NE; ++e) mx = fmaxf(mx, lg[e]);
    float ssum = 0.f;
#pragma unroll
    for (int e = 0; e < NE; ++e) { lg[e] = __expf(lg[e] - mx); ssum += lg[e]; }
    float inv = SCALING / ssum;
    int e = k8 >> 1;                                 // expert for this 8-col chunk
    float ge = 0.f;
#pragma unroll
    for (int e2 = 0; e2 < NE; ++e2) if (e2 == e) ge = lg[e2];
    ge *= inv;
    float hv[8] = {0.f, 0.f, 0.f, 0.f, 0.f, 0.f, 0.f, 0.f};
#pragma unroll
    for (int s = 0; s < KSPLIT; ++s) {
        const float* hs = hb + (size_t)s * NROWS * NG;
        float4 h0 = *(const float4*)&hs[k8 * 8];
        float4 h1 = *(const float4*)&hs[k8 * 8 + 4];
        hv[0] += h0.x; hv[1] += h0.y; hv[2] += h0.z; hv[3] += h0.w;
        hv[4] += h1.x; hv[5] += h1.y; hv[6] += h1.z; hv[7] += h1.w;
    }
    bf8pack p;
#pragma unroll
    for (int i = 0; i < 8; ++i) p.h[i] = __float2bfloat16(hv[i] * ge);
    *(bf16x8*)&Xcat[(size_t)n * KC + IN_F + k8 * 8] = p.v;
}

// ==================== 256x256 8-phase main GEMM (T2+T3+T4+T5) ====================
// out[8192][4096] = Xcat @ Wcat^T, K=4224 = 66 tiles of BK=64 -> 33 iters x 2 tiles.
// 512 threads = 8 waves (2M x 4N), per-wave C = 128x64 = acc[8][4].
// LDS 128 KiB STATIC = 2 dbuf x {A,B} x {lo,hi} half-tiles of 128x64 bf16 (16 KiB each).
//
// SLOT SEMANTICS (round-3 lesson): A-lo/A-hi are M-HALVES selected per-wave by wm;
// B-lo/B-hi are N-halves selected by wn>>1. A wave reads its ONE A slot in EVERY
// phase containing DS_A on that buf, and its ONE B slot in every DS_B phase.
// True lifetimes per buf-visit: B slots die at the 2nd quadrant phase, A slots at
// the 3rd. Staging must respect THOSE, not quadrant labels.
//
// Quadrant order (round-2, proven): (mlo,nlo)->(mlo,nhi)->(mhi,nhi)->(mhi,nlo);
// reads 12/4/8/0 per phase; bl+bh register-held. Uniform staging, 1 half-tile/phase:
//   P1: buf1.A-lo(t2i+1) | P2: buf1.A-hi(t2i+1) | P3: buf0.B-lo(t2i+2) | P4: buf0.B-hi
//   P5: buf0.A-lo        | P6: buf0.A-hi        | P7: buf1.B-lo(t2i+3) | P8: buf1.B-hi
// WAR: buf0.B read P1,P2 -> staged P3,P4 ok | buf0.A read P1,P3 -> staged P5,P6 ok
//      buf1.B read P5,P6 -> staged P7,P8 ok | buf1.A read P5,P7 -> staged P1,P2 ok.
// vmcnt(4) ledger (2 loads/phase): after P8 vmcnt(4) -> {P7,P8} in flight; P1..P4
//   add 8 -> 12; vmcnt(4)@P4 retires prevP7,prevP8,P1,P2 = buf1 tile complete before
//   P5 reads. Symmetric @P8 retires P3..P6 = buf0 tile complete before next P1.
//   Never drains to 0 in-loop.
// XOR chunk swizzle (chunk ^= row&7) on BOTH stage-source and ds_read (rule 21).

#define BARRIER() __builtin_amdgcn_s_barrier()
#define SBAR()    __builtin_amdgcn_sched_barrier(0)
#define LGKM0()   do { asm volatile("s_waitcnt lgkmcnt(0)" ::: "memory"); SBAR(); } while (0)
#define VMCNT4()  asm volatile("s_waitcnt vmcnt(4)" ::: "memory")
#define VMCNT0()  asm volatile("s_waitcnt vmcnt(0)" ::: "memory")
#define PRIO(x)   __builtin_amdgcn_s_setprio(x)

// slot(buf, op, half) element base = (buf*4 + op*2 + half) * 8192; op 0=A, 1=B
#define STAGE(buf, op, half, koff) do {                                               \
        const __hip_bfloat16* _g = ((op) ? gB : gA) + (size_t)(half) * 128 * KC + (koff); \
        __hip_bfloat16* _l = lds + ((buf) * 4 + (op) * 2 + (half)) * 8192 + tid * 8;  \
        gl_lds16(_g, _l);                                                             \
        gl_lds16(_g + (size_t)64 * KC, _l + 4096);                                    \
    } while (0)

#define DS_A(b, mbase) do {                                                           \
        _Pragma("unroll") for (int mi = 0; mi < 4; ++mi) {                            \
            const __hip_bfloat16* _p = As[b] + (((mbase) + mi) * 16 + l16) * 64;      \
            a[mi][0] = *(const bf16x8*)(_p + kc0);                                    \
            a[mi][1] = *(const bf16x8*)(_p + kc1);                                    \
        } } while (0)

#define DS_B(b, dst, nbase) do {                                                      \
        _Pragma("unroll") for (int nj = 0; nj < 2; ++nj) {                            \
            const __hip_bfloat16* _p = Bs[b] + (brow0 + ((nbase) + nj) * 16 + l16) * 64; \
            dst[nj][0] = *(const bf16x8*)(_p + kc0);                                  \
            dst[nj][1] = *(const bf16x8*)(_p + kc1);                                  \
        } } while (0)

#define MM(mb, dst, nb) do {                                                          \
        _Pragma("unroll") for (int mi = 0; mi < 4; ++mi)                              \
        _Pragma("unroll") for (int nj = 0; nj < 2; ++nj) {                            \
            acc[(mb) + mi][(nb) + nj] = __builtin_amdgcn_mfma_f32_16x16x32_bf16(      \
                a[mi][0], dst[nj][0], acc[(mb) + mi][(nb) + nj], 0, 0, 0);            \
            acc[(mb) + mi][(nb) + nj] = __builtin_amdgcn_mfma_f32_16x16x32_bf16(      \
                a[mi][1], dst[nj][1], acc[(mb) + mi][(nb) + nj], 0, 0, 0);            \
        } } while (0)

__global__ __launch_bounds__(512, 2) void k_gemm(const __hip_bfloat16* __restrict__ Xcat,
                                                 const __hip_bfloat16* __restrict__ Wcat,
                                                 float* __restrict__ out) {
    __shared__ __hip_bfloat16 lds[8 * 8192];    // 8 x 16 KiB half-tile slots = 128 KiB static
    const int tid  = threadIdx.x;
    const int lane = tid & 63;
    const int w    = tid >> 6;                  // 0..7
    const int wm   = w >> 2, wn = w & 3;        // 2M x 4N waves
    const int quad = lane >> 4;
    const int l16  = lane & 15;
    const int xr   = l16 & 7;

    // XCD-bijective swizzle (512 % 8 == 0 -> simple form bijective)
    const int bid = blockIdx.x;
    const int swz = (bid & 7) * 64 + (bid >> 3);
    const int m0  = (swz >> 4) * 256;           // 32 M-blocks
    const int n0  = (swz & 15) * 256;           // 16 N-blocks

    // staging addresses: thread t covers rows {srow, srow+64} of a half-tile,
    // global chunk = (t&7) ^ (srow&7)  (LDS stays linear; source pre-swizzled)
    const int srow = tid >> 3;
    const int scol = ((tid & 7) ^ (srow & 7)) << 3;
    const __hip_bfloat16* gA = Xcat + (size_t)(m0 + srow) * KC + scol;
    const __hip_bfloat16* gB = Wcat + (size_t)(n0 + srow) * KC + scol;

    // reader slot bases: wave reads ONE A half (by wm) and ONE B half (by wn>>1)
    const __hip_bfloat16* As[2] = { lds + (0 + wm) * 8192,        lds + (4 + wm) * 8192 };
    const __hip_bfloat16* Bs[2] = { lds + (2 + (wn >> 1)) * 8192, lds + (6 + (wn >> 1)) * 8192 };
    const int brow0 = (wn & 1) * 64;
    const int kc0 = (quad ^ xr) * 8;            // k-chunk swizzled (elems)
    const int kc1 = ((4 + quad) ^ xr) * 8;

    f32x4 acc[8][4];
#pragma unroll
    for (int i = 0; i < 8; ++i)
#pragma unroll
        for (int j = 0; j < 4; ++j)
            acc[i][j] = (f32x4){0.f, 0.f, 0.f, 0.f};
    bf16x8 a[4][2], bl[2][2], bh[2][2];

    // ---- prologue: t0 {B-lo,B-hi,A-lo,A-hi} + t1 {B-lo,B-hi}; vmcnt(4) retires t0 ----
    STAGE(0, 1, 0, 0);    // t0.B-lo
    STAGE(0, 1, 1, 0);    // t0.B-hi
    STAGE(0, 0, 0, 0);    // t0.A-lo
    STAGE(0, 0, 1, 0);    // t0.A-hi
    STAGE(1, 1, 0, 64);   // t1.B-lo
    STAGE(1, 1, 1, 64);   // t1.B-hi
    VMCNT4();
    BARRIER(); SBAR();

#pragma unroll 1
    for (int i = 0; i < 33; ++i) {
        const int kb    = i * 128;
        const int t1off = kb + 64;                                    // tile 2i+1 (always valid)
        const int s0off = (kb + 128 <= KC - 64) ? kb + 128 : KC - 64; // tile 2i+2 (clamped)
        const int s1off = (kb + 192 <= KC - 64) ? kb + 192 : KC - 64; // tile 2i+3 (clamped)

        // P1: Q(mlo,nlo) buf0; reads A(12: mbase0-3 + B-lo); stage buf1.A-lo (read prevP5/P7)
        DS_A(0, 0); DS_B(0, bl, 0);
        STAGE(1, 0, 0, t1off);
        BARRIER(); LGKM0();
        PRIO(1); MM(0, bl, 0); PRIO(0);
        BARRIER(); SBAR();

        // P2: Q(mlo,nhi) buf0; reads B-hi(4), a held; stage buf1.A-hi (read prevP5/P7)
        DS_B(0, bh, 2);
        STAGE(1, 0, 1, t1off);
        BARRIER(); LGKM0();
        PRIO(1); MM(0, bh, 2); PRIO(0);
        BARRIER(); SBAR();

        // P3: Q(mhi,nhi) buf0; reads A mbase4-7(8), bh held; stage buf0.B-lo (B died P2)
        DS_A(0, 4);
        STAGE(0, 1, 0, s0off);
        BARRIER(); LGKM0();
        PRIO(1); MM(4, bh, 2); PRIO(0);
        BARRIER(); SBAR();

        // P4: Q(mhi,nlo) buf0; regs only (a from P3, bl from P1); stage buf0.B-hi;
        //     vmcnt(4) retires prevP7,prevP8,P1,P2 => buf1 (tile 2i+1) fully landed
        STAGE(0, 1, 1, s0off);
        BARRIER(); LGKM0();
        PRIO(1); MM(4, bl, 0); PRIO(0);
        VMCNT4();
        BARRIER(); SBAR();

        // P5: Q(mlo,nlo) buf1; stage buf0.A-lo (A died P3)
        DS_A(1, 0); DS_B(1, bl, 0);
        STAGE(0, 0, 0, s0off);
        BARRIER(); LGKM0();
        PRIO(1); MM(0, bl, 0); PRIO(0);
        BARRIER(); SBAR();

        // P6: Q(mlo,nhi) buf1; stage buf0.A-hi (A died P3)
        DS_B(1, bh, 2);
        STAGE(0, 0, 1, s0off);
        BARRIER(); LGKM0();
        PRIO(1); MM(0, bh, 2); PRIO(0);
        BARRIER(); SBAR();

        // P7: Q(mhi,nhi) buf1; stage buf1.B-lo (buf1.B died P6)
        DS_A(1, 4);
        STAGE(1, 1, 0, s1off);
        BARRIER(); LGKM0();
        PRIO(1); MM(4, bh, 2); PRIO(0);
        BARRIER(); SBAR();

        // P8: Q(mhi,nlo) buf1; regs only; stage buf1.B-hi (buf1.B died P6);
        //     vmcnt(4) retires P3..P6 => buf0 (tile 2i+2) fully landed
        STAGE(1, 1, 1, s1off);
        BARRIER(); LGKM0();
        PRIO(1); MM(4, bl, 0); PRIO(0);
        VMCNT4();
        BARRIER(); SBAR();
    }
    VMCNT0();   // drain the 4 in-flight (clamped) epilogue loads before endpgm

    // ---- C-write: row = m0 + wm*128 + ti*16 + quad*4 + r ; col = n0 + wn*64 + tj*16 + l16 ----
#pragma unroll
    for (int ti = 0; ti < 8; ++ti)
#pragma unroll
        for (int tj = 0; tj < 4; ++tj) {
            int col = n0 + wn * 64 + tj * 16 + l16;
#pragma unroll
            for (int r = 0; r < 4; ++r) {
                int row = m0 + wm * 128 + ti * 16 + quad * 4 + r;
                out[(size_t)row * OUT_F + col] = acc[ti][tj][r];
            }
        }
}

extern "C" void kernel_launch(void* const* d_in, const int* in_sizes, int n_in,
                              void* d_out, int out_size, void* d_ws, size_t ws_size,
                              hipStream_t stream) {
    const float* x  = (const float*)d_in[0];   // [8192, 4096]
    const float* W0 = (const float*)d_in[1];   // [4096, 4096]
    const float* Wg = (const float*)d_in[2];   // [8, 4096]
    const float* A  = (const float*)d_in[3];   // [8, 16, 4096]
    const float* B  = (const float*)d_in[4];   // [8, 4096, 16]
    float* out = (float*)d_out;

    char* ws = (char*)d_ws;
    size_t off = 0;
    __hip_bfloat16* Xcat = (__hip_bfloat16*)(ws + off); off += (size_t)NROWS * KC * 2;        // 69.2 MB
    __hip_bfloat16* Wcat = (__hip_bfloat16*)(ws + off); off += (size_t)OUT_F * KC * 2;        // 34.6 MB
    __hip_bfloat16* AG   = (__hip_bfloat16*)(ws + off); off += (size_t)NG * IN_F * 2;         // 1.2 MB
    float*          H    = (float*)(ws + off);          off += (size_t)KSPLIT * NROWS * NG * 4; // 18.9 MB

    k_prep<<<PREP_GRID, 256, 0, stream>>>(W0, B, A, Wg, x, Wcat, AG, Xcat);
    k_hgemm<<<dim3(NROWS / 64, KSPLIT), 256, 0, stream>>>(Xcat, AG, H);
    k_gate<<<(NROWS * 16) / 256, 256, 0, stream>>>(H, Xcat);
    k_gemm<<<512, 512, 0, stream>>>(Xcat, Wcat, out);
}